// Round 13
// baseline (147.855 us; speedup 1.0000x reference)
//
#include <hip/hip_runtime.h>
#include <hip/hip_bf16.h>
#include <math.h>

// Problem constants
#define B_    8
#define T_    2048
#define NTOK  (B_ * T_)   // 16384 tokens
#define D_    512
#define E_    8
#define NPAIR 28          // unordered expert pairs (top-2 always distinct)
#define CAP   NTOK        // per-pair bucket capacity
#define CPAD  32          // counter padding: one counter per 128B line
#define NREP  8           // counter replicas per pair (indexed by bid&7)
#define RSEG  2048        // entries segment per (pair, replica): 128 blk x 16 tok

// gemm mtile grain = 64 rows. Sum ceil(cnt_p/64) <= 256 + 27 = 283 -> 288
#define GEMM_MTILES 288   // multiple of 8 for the XCD id decode

// router: 1024 blocks x 256 thr; 16 tok/block, 4 tok/wave, 1 tok/lane.
#define RV_TOK    16
#define RV_THR    256
#define WSH_FULL  8448    // full-depth skewed W: 512*16 + 64*4 floats (33.8 KB)

// fused prep kernel: router blocks first (long pole), then transpose blocks
#define PREP_ROUTER_BLOCKS (NTOK / RV_TOK)         // 1024
#define PREP_TRANS_BLOCKS  (8 * 8 * E_)            // 512 (64x64 tiles)
#define PREP_BLOCKS (PREP_ROUTER_BLOCKS + PREP_TRANS_BLOCKS)  // 1536

typedef __attribute__((ext_vector_type(4))) float f32x4;
typedef __attribute__((ext_vector_type(8))) short short8;  // 8 bf16 (MFMA a/b frag)

__device__ __forceinline__ void async_load16(const void* g, void* l) {
    __builtin_amdgcn_global_load_lds(
        (const __attribute__((address_space(1))) unsigned int*)g,
        (__attribute__((address_space(3))) unsigned int*)l,
        16, 0, 0);
}

// ---------------------------------------------------------------------------
// Kernel 1 (fused prep): transpose_wk  U  router(+bucket).
//   R13 vs R11/R12: pair counters REPLICATED 8x (replica = bid&7; 224
//   line-padded counters). R12's direct read: prep = 45.6us, largest
//   dispatch; residue explained by the counts-atomic queue drain (~450
//   serialized ops/line x 21ns [R3-measured] ~ 10us, with ALL 1024 router
//   blocks resident and parked on the atomic return). Replication cuts
//   per-line ops to ~56 (~1.2us). Entries become segmented:
//   entries[p][rep*RSEG + slot]; per-(p,rep) worst case = 128 blocks x 16
//   tok = 2048 = RSEG exactly (capacity proof). Router/transpose bodies
//   otherwise unchanged from R11.
// ---------------------------------------------------------------------------
__global__ __launch_bounds__(256) void prep_kernel(
    const float* __restrict__ x,     // [NTOK][D]
    const float* __restrict__ eps,   // [NTOK][E]
    const float* __restrict__ Wr,    // [D][E]
    const float* __restrict__ br,    // [E]
    const float* __restrict__ Wn,    // [D][E]
    const float* __restrict__ bn,    // [E]
    const float* __restrict__ Wk,    // [E][D][D]
    __hip_bfloat16* __restrict__ xb,   // out: [NTOK][D] bf16
    __hip_bfloat16* __restrict__ wkt,  // out: [E][D][D] bf16 (B^T)
    int* __restrict__ counts,          // [NPAIR*NREP*CPAD] pre-zeroed
    uint4* __restrict__ entries)       // [NPAIR][NREP][RSEG]
{
    __shared__ float smem[WSH_FULL];   // 33.8 KB (W skewed; transpose reuses)
    __shared__ int hist[NPAIR];
    __shared__ int basep[NPAIR];
    const int bid = blockIdx.x, tid = threadIdx.x;

    if (bid < PREP_ROUTER_BLOCKS) {
        // ------------------------- router body -------------------------
        float* wsh = smem;   // full-depth skewed W: row k at k*16 + (k>>3)*4
        const int rep = bid & (NREP - 1);

        const int tok0 = bid * RV_TOK;
        const int lane = tid & 63, wv = tid >> 6;
        const int kidx = lane >> 2, ts = lane & 3;
        const int tl = wv * 4 + ts;                // this lane's token
        const int tok = tok0 + tl;

        if (tid < NPAIR) hist[tid] = 0;

        // ---- issue ALL x loads up-front (8 f32x4 -> 32 regs, no LDS) ----
        const float* xrow = x + (size_t)tok * D_ + kidx * 8;
        f32x4 xr[4][2];
        #pragma unroll
        for (int c = 0; c < 4; ++c) {
            xr[c][0] = *(const f32x4*)(xrow + c * 128);
            xr[c][1] = *(const f32x4*)(xrow + c * 128 + 4);
        }

        // ---- stage FULL W once: 1024 (k,half) rows over 4 iterations ----
        #pragma unroll
        for (int it = 0; it < 4; ++it) {
            const int idx = it * RV_THR + tid;     // [0,1024)
            const int k = idx >> 1, h = idx & 1;   // k row, Wr/Wn half
            const float* srcw = (h ? Wn : Wr) + (size_t)k * E_;
            const f32x4 w0 = *(const f32x4*)(srcw);
            const f32x4 w1 = *(const f32x4*)(srcw + 4);
            float* dstw = wsh + k * 16 + (k >> 3) * 4 + h * 8;
            *(f32x4*)(dstw)     = w0;
            *(f32x4*)(dstw + 4) = w1;
        }
        __syncthreads();   // barrier 1: W visible

        float acc[16];  // [0..7]=x.Wr per expert, [8..15]=x.Wn
        #pragma unroll
        for (int c = 0; c < 16; ++c) acc[c] = 0.f;

        #pragma unroll
        for (int c = 0; c < 4; ++c) {
            // fused xb bf16 write straight from regs (coalesced 256B rows)
            union { __hip_bfloat16 h4[8]; uint4 u; } cv;
            #pragma unroll
            for (int j = 0; j < 4; ++j) {
                cv.h4[j]     = __float2bfloat16(xr[c][0][j]);
                cv.h4[4 + j] = __float2bfloat16(xr[c][1][j]);
            }
            *(uint4*)(xb + (size_t)tok * D_ + c * 128 + kidx * 8) = cv.u;

            // FMAs vs LDS-resident W (chunk base telescopes to c*2112)
            const float* wbase = wsh + c * 2112 + kidx * 132;
            #pragma unroll
            for (int kk = 0; kk < 8; ++kk) {
                const float xav = (kk < 4) ? xr[c][0][kk] : xr[c][1][kk - 4];
                const float* wrow = wbase + kk * 16;
                #pragma unroll
                for (int c4 = 0; c4 < 4; ++c4) {
                    const f32x4 w = *(const f32x4*)(wrow + c4 * 4);
                    #pragma unroll
                    for (int cc = 0; cc < 4; ++cc)
                        acc[c4 * 4 + cc] = fmaf(xav, w[cc], acc[c4 * 4 + cc]);
                }
            }
        }

        // reduce across the 16 kidx lanes (stride 4): xor 4,8,16,32
        #pragma unroll
        for (int off = 4; off < 64; off <<= 1) {
            #pragma unroll
            for (int c = 0; c < 16; ++c)
                acc[c] += __shfl_xor(acc[c], off);
        }

        // ---- top-2 + two-level bucket (LDS hist -> replicated counters) ----
        int p_ = 0, l_ = 0;
        float gae_ = 0.f, gbe_ = 0.f;
        const bool writer = (lane < 4);
        if (writer) {  // kidx==0 lanes hold full dots for token tl
            float nvv[8];
            #pragma unroll
            for (int e = 0; e < 8; ++e) {
                const float nl = acc[8 + e] + bn[e];
                // jax.nn.softplus = max(z,0) + log1p(exp(-|z|))
                const float sp = fmaxf(nl, 0.f) + log1pf(expf(-fabsf(nl)));
                nvv[e] = acc[e] + br[e] + eps[(size_t)tok * E_ + e] * sp;
            }
            // top-2, lax.top_k tie semantics (lowest index wins ties)
            int i1 = 0; float v1 = nvv[0];
            #pragma unroll
            for (int e = 1; e < 8; ++e)
                if (nvv[e] > v1) { v1 = nvv[e]; i1 = e; }
            int i2 = -1; float v2 = -3.4e38f;
            #pragma unroll
            for (int e = 0; e < 8; ++e)
                if (e != i1 && nvv[e] > v2) { v2 = nvv[e]; i2 = e; }
            const float t  = expf(v2 - v1);
            const float g1 = 1.f / (1.f + t);
            const float g2 = t / (1.f + t);
            const int aa = min(i1, i2), bb = max(i1, i2);
            gae_ = (i1 < i2) ? g1 : g2;   // gate of expert aa
            gbe_ = (i1 < i2) ? g2 : g1;   // gate of expert bb
            p_ = aa * (15 - aa) / 2 + (bb - aa - 1);
            l_ = atomicAdd(&hist[p_], 1);            // LDS atomic (cheap)
        }
        __syncthreads();   // barrier 2: hist complete
        if (tid < NPAIR && hist[tid] > 0)
            basep[tid] = atomicAdd(counts + (tid * NREP + rep) * CPAD,
                                   hist[tid]);       // replica line (low contention)
        __syncthreads();   // barrier 3: basep ready
        if (writer)
            entries[(size_t)p_ * CAP + rep * RSEG + basep[p_] + l_] =
                make_uint4((unsigned)tok, __float_as_uint(gae_),
                           __float_as_uint(gbe_), 0u);
    } else {
        // ------------------- transpose body (64x64 tiles) ------------------
        const int idx = bid - PREP_ROUTER_BLOCKS;   // [0, 512)
        const int e  = idx >> 6;
        const int rem = idx & 63;
        const int d0 = (rem & 7) * 64;
        const int h0 = (rem >> 3) * 64;
        const int tx = tid & 63, ty = tid >> 6;     // 64 x 4
        float (*tile)[65] = reinterpret_cast<float(*)[65]>(smem);  // 16.6 KB

        const float* src = Wk + ((size_t)e * D_ + d0) * D_ + h0;
        #pragma unroll
        for (int r = ty; r < 64; r += 4)
            tile[r][tx] = src[(size_t)r * D_ + tx];
        __syncthreads();
        __hip_bfloat16* dst = wkt + ((size_t)e * D_ + h0) * D_ + d0;
        #pragma unroll
        for (int r = ty; r < 64; r += 4)
            dst[(size_t)r * D_ + tx] = __float2bfloat16(tile[tx][r]);
    }
    // (no fence, no done-counter: kernel boundary publishes everything)
}

// ---------------------------------------------------------------------------
// Kernel 2: pair-grouped expert GEMM, DIRECT output. Core = R11 exactly
// (the measured best: BN=128, (256,3), split K-step, counted vmcnt(5), XOR
// swizzle, setprio, inline worklist). R13 delta: counts are summed over the
// 8 replicas, and the ent[] gather maps logical index -> (replica, slot)
// through an 8-entry segment walk staged in LDS.
// ---------------------------------------------------------------------------
__global__ __launch_bounds__(256, 3) void moe_gemm(
    const __hip_bfloat16* __restrict__ xb,   // [NTOK][D] bf16
    const __hip_bfloat16* __restrict__ wkt,  // [E][D(out)][D(in)] bf16 (B^T)
    const float* __restrict__ bk,            // [E][D]
    const int* __restrict__ counts,          // [NPAIR*NREP*CPAD]
    const uint4* __restrict__ entries,       // [NPAIR][NREP][RSEG]
    float* __restrict__ out)                 // [NTOK][D] fp32 (fully written)
{
    constexpr int BM = 64, BN = 128, BK = 32;
    constexpr int NT = D_ / BK;  // 16 K-steps
    __shared__ __hip_bfloat16 As[2][BM * BK];       // 2 x 4 KB
    __shared__ __hip_bfloat16 Bs[2][2][BN * BK];    // 2 x 16 KB
    __shared__ uint4 ent[BM];                       // 1 KB
    __shared__ int cseg[NREP];                      // replica counts for pair p

    // id = g*32 + nt*8 + j ; mtile mi = g*8 + j ; XCD = id%8 = j for all 4 nt
    const int id = blockIdx.x;
    const int g = id >> 5, rdec = id & 31;
    const int nt = rdec >> 3;
    const int mi = g * 8 + (rdec & 7);

    const int tid = threadIdx.x;
    const int wave = tid >> 6, lane = tid & 63;

    // ---- inline worklist: lane-parallel scan of ceil(sum-counts/64) ----
    int cval = 0;
    if (lane < NPAIR) {
        #pragma unroll
        for (int r = 0; r < NREP; ++r)
            cval += counts[(lane * NREP + r) * CPAD];
    }
    const int nm = (cval + 63) >> 6;
    int inc = nm;
    #pragma unroll
    for (int d = 1; d < 32; d <<= 1) {
        const int v = __shfl_up(inc, d);
        if (lane >= d) inc += v;
    }
    const int total = __shfl(inc, NPAIR - 1);
    if (mi >= total) return;
    const int ex = inc - nm;   // exclusive prefix for this lane's pair
    const unsigned long long hit =
        __ballot(lane < NPAIR && mi >= ex && mi < ex + nm);
    const int p = __ffsll(hit) - 1;
    const int mt = mi - __shfl(ex, p);
    const int cnt = __shfl(cval, p);

    // decode pair p -> (e1 < e2)
    int e1 = 0, rem = p;
    while (rem >= 7 - e1) { rem -= 7 - e1; ++e1; }
    const int e2 = e1 + 1 + rem;

    // stage replica counts for pair p, then segmented ent gather
    if (tid < NREP) cseg[tid] = counts[(p * NREP + tid) * CPAD];
    __syncthreads();
    if (tid < BM) {
        const int idx = mt * BM + tid;
        if (idx < cnt) {
            int rr = 0, rem2 = idx;
            while (rr < NREP - 1 && rem2 >= cseg[rr]) { rem2 -= cseg[rr]; ++rr; }
            ent[tid] = entries[(size_t)p * CAP + rr * RSEG + rem2];
        } else {
            ent[tid] = make_uint4(0u, 0u, 0u, 0u);
        }
    }
    __syncthreads();

    const int quad = lane >> 4, lr = lane & 15;
    const int wm = wave >> 1, wn = wave & 1;   // wave tile: rows wm*32, cols wn*64

    // --- staging geometry (64B contiguous per row, 16 rows per call) ---
    const int r16 = lane >> 2;
    const int csel = (lane & 3) ^ ((lane >> 3) & 3);   // swizzled 16B chunk
    const size_t tA0 = ent[wave * 16 + r16].x;
    const __hip_bfloat16* gA0 = xb + tA0 * D_ + csel * 8;
    const __hip_bfloat16* gB1 = wkt + ((size_t)e1 * D_ + nt * BN + wave * 32 + r16) * D_ + csel * 8;
    const __hip_bfloat16* gB2 = wkt + ((size_t)e2 * D_ + nt * BN + wave * 32 + r16) * D_ + csel * 8;

    // read-side swizzled slot (per-lane constant): quad ^ ((lr>>1)&3)
    const int so = (quad ^ ((lr >> 1) & 3)) * 8;

    f32x4 accA[2][4], accB[2][4];
    #pragma unroll
    for (int i = 0; i < 2; ++i)
        #pragma unroll
        for (int j = 0; j < 4; ++j) {
            accA[i][j] = (f32x4){0.f, 0.f, 0.f, 0.f};
            accB[i][j] = (f32x4){0.f, 0.f, 0.f, 0.f};
        }

    // 5 async loads per wave per STAGE -> vmcnt counts in units of 5
#define STAGE(buf, k0) do {                                        \
        __hip_bfloat16* aB  = &As[buf][wave * 512];                \
        __hip_bfloat16* b1B = &Bs[buf][0][wave * 1024];            \
        __hip_bfloat16* b2B = &Bs[buf][1][wave * 1024];            \
        async_load16(gA0 + (k0), aB);                              \
        async_load16(gB1 + (k0), b1B);                             \
        async_load16(gB1 + 16 * D_ + (k0), b1B + 512);             \
        async_load16(gB2 + (k0), b2B);                             \
        async_load16(gB2 + 16 * D_ + (k0), b2B + 512);             \
    } while (0)

#define READS(buf) do {                                                        \
        _Pragma("unroll")                                                      \
        for (int i = 0; i < 2; ++i)                                            \
            a[i] = *(const short8*)(&As[buf][(wm * 32 + i * 16 + lr) * 32 + so]); \
        _Pragma("unroll")                                                      \
        for (int j = 0; j < 4; ++j) {                                          \
            b1v[j] = *(const short8*)(&Bs[buf][0][(wn * 64 + j * 16 + lr) * 32 + so]); \
            b2v[j] = *(const short8*)(&Bs[buf][1][(wn * 64 + j * 16 + lr) * 32 + so]); \
        }                                                                      \
    } while (0)

#define MFMAS() do {                                                           \
        __builtin_amdgcn_s_setprio(1);                                         \
        _Pragma("unroll")                                                      \
        for (int i = 0; i < 2; ++i)                                            \
            _Pragma("unroll")                                                  \
            for (int j = 0; j < 4; ++j) {                                      \
                accA[i][j] = __builtin_amdgcn_mfma_f32_16x16x32_bf16(          \
                    a[i], b1v[j], accA[i][j], 0, 0, 0);                        \
                accB[i][j] = __builtin_amdgcn_mfma_f32_16x16x32_bf16(          \
                    a[i], b2v[j], accB[i][j], 0, 0, 0);                        \
            }                                                                  \
        __builtin_amdgcn_s_setprio(0);                                         \
    } while (0)

    // prologue: tiles 0 and 1 in flight (10 outstanding VMEM ops per wave)
    STAGE(0, 0);
    STAGE(1, BK);

    // steady state (split K-step): tile t lands -> read to regs -> drain
    // lgkm -> barrier -> refill the SAME buffer with tile t+2 -> MFMA.
    for (int t = 0; t < NT - 1; ++t) {
        short8 a[2], b1v[4], b2v[4];
        asm volatile("s_waitcnt vmcnt(5)" ::: "memory");
        __builtin_amdgcn_s_barrier();
        READS(t & 1);
        asm volatile("s_waitcnt lgkmcnt(0)" ::: "memory");
        __builtin_amdgcn_s_barrier();
        if (t + 2 < NT) STAGE(t & 1, (t + 2) * BK);
        MFMAS();
    }
    {
        short8 a[2], b1v[4], b2v[4];
        asm volatile("s_waitcnt vmcnt(0)" ::: "memory");
        __builtin_amdgcn_s_barrier();
        READS((NT - 1) & 1);
        MFMAS();
    }

#undef STAGE
#undef READS
#undef MFMAS

    const int colbase = nt * BN + wn * 64 + lr;
    float bkA[4], bkB[4];
    #pragma unroll
    for (int j = 0; j < 4; ++j) {
        bkA[j] = bk[e1 * D_ + colbase + j * 16];
        bkB[j] = bk[e2 * D_ + colbase + j * 16];
    }

    #pragma unroll
    for (int i = 0; i < 2; ++i) {
        #pragma unroll
        for (int rr = 0; rr < 4; ++rr) {
            const int row = wm * 32 + i * 16 + quad * 4 + rr;  // C: row = quad*4+reg
            if (mt * BM + row < cnt) {
                const uint4 en = ent[row];
                const float ga = __uint_as_float(en.y);
                const float gb = __uint_as_float(en.z);
                float* orow = out + (size_t)en.x * D_ + colbase;
                #pragma unroll
                for (int j = 0; j < 4; ++j)
                    orow[j * 16] = ga * (accA[i][j][rr] + bkA[j])
                                 + gb * (accB[i][j][rr] + bkB[j]);
            }
        }
    }
}

// ---------------------------------------------------------------------------
// Launch: 3 dispatches: memset, fused prep, gemm (worklist inlined).
// ---------------------------------------------------------------------------
extern "C" void kernel_launch(void* const* d_in, const int* in_sizes, int n_in,
                              void* d_out, int out_size, void* d_ws, size_t ws_size,
                              hipStream_t stream) {
    const float* x   = (const float*)d_in[0];
    const float* eps = (const float*)d_in[1];
    const float* Wr  = (const float*)d_in[2];
    const float* br  = (const float*)d_in[3];
    const float* Wn  = (const float*)d_in[4];
    const float* bn  = (const float*)d_in[5];
    const float* Wk  = (const float*)d_in[6];
    const float* bk  = (const float*)d_in[7];
    float* out = (float*)d_out;

    // workspace layout (256B-aligned): ~28 MB total
    char* ws = (char*)d_ws;
    size_t off = 0;
    int* counts = (int*)(ws + off);                     off += 32768; // NPAIR*NREP*CPAD ints (28.7KB)
    uint4* entries = (uint4*)(ws + off);                off += (size_t)NPAIR * CAP * 16;  // 7.3 MiB
    __hip_bfloat16* xb = (__hip_bfloat16*)(ws + off);   off += (size_t)NTOK * D_ * 2;     // 16 MiB
    __hip_bfloat16* wkt = (__hip_bfloat16*)(ws + off);  off += (size_t)E_ * D_ * D_ * 2;  // 4 MiB
    (void)ws_size;

    hipMemsetAsync(counts, 0, 32768, stream);   // zeroes all replica counters

    prep_kernel<<<dim3(PREP_BLOCKS), dim3(256), 0, stream>>>(
        x, eps, Wr, br, Wn, bn, Wk, xb, wkt, counts, entries);
    moe_gemm<<<dim3(GEMM_MTILES * 4), dim3(256), 0, stream>>>(
        xb, wkt, bk, counts, entries, out);
}

// Round 14
// 145.540 us; speedup vs baseline: 1.0159x; 1.0159x over previous
//
#include <hip/hip_runtime.h>
#include <hip/hip_bf16.h>
#include <math.h>

// Problem constants
#define B_    8
#define T_    2048
#define NTOK  (B_ * T_)   // 16384 tokens
#define D_    512
#define E_    8
#define NPAIR 28          // unordered expert pairs (top-2 always distinct)
#define CAP   NTOK        // per-pair bucket capacity (worst case)
#define CPAD  32          // counts padding: one counter per 128B line

// gemm mtile grain = 64 rows. Sum ceil(cnt_p/64) <= 256 + 27 = 283 -> 288
#define GEMM_MTILES 288   // multiple of 8 for the XCD id decode

// router: 1024 blocks x 256 thr; 16 tok/block, 4 tok/wave, 1 tok/lane.
#define RV_TOK    16
#define RV_THR    256
#define WSH_FULL  8448    // full-depth skewed W: 512*16 + 64*4 floats (33.8 KB)

// fused prep kernel: router blocks first (long pole), then transpose blocks
#define PREP_ROUTER_BLOCKS (NTOK / RV_TOK)         // 1024
#define PREP_TRANS_BLOCKS  (8 * 8 * E_)            // 512 (64x64 tiles)
#define PREP_BLOCKS (PREP_ROUTER_BLOCKS + PREP_TRANS_BLOCKS)  // 1536

typedef __attribute__((ext_vector_type(4))) float f32x4;
typedef __attribute__((ext_vector_type(8))) short short8;  // 8 bf16 (MFMA a/b frag)

__device__ __forceinline__ void async_load16(const void* g, void* l) {
    __builtin_amdgcn_global_load_lds(
        (const __attribute__((address_space(1))) unsigned int*)g,
        (__attribute__((address_space(3))) unsigned int*)l,
        16, 0, 0);
}

// ---------------------------------------------------------------------------
// Kernel 1 (fused prep): transpose_wk  U  router(+bucket). R11 verbatim
// (the measured best, 146.3us total): x reg-direct (no LDS bounce), full-W
// staged once, 3 barriers/block, two-level bucket (LDS hist -> line-padded
// counter atomics), 64x64 transpose tiles.
// ---------------------------------------------------------------------------
__global__ __launch_bounds__(256) void prep_kernel(
    const float* __restrict__ x,     // [NTOK][D]
    const float* __restrict__ eps,   // [NTOK][E]
    const float* __restrict__ Wr,    // [D][E]
    const float* __restrict__ br,    // [E]
    const float* __restrict__ Wn,    // [D][E]
    const float* __restrict__ bn,    // [E]
    const float* __restrict__ Wk,    // [E][D][D]
    __hip_bfloat16* __restrict__ xb,   // out: [NTOK][D] bf16
    __hip_bfloat16* __restrict__ wkt,  // out: [E][D][D] bf16 (B^T)
    int* __restrict__ counts,          // [NPAIR*CPAD] pre-zeroed (line-padded)
    uint4* __restrict__ entries)       // [NPAIR][CAP]
{
    __shared__ float smem[WSH_FULL];   // 33.8 KB (W skewed; transpose reuses)
    __shared__ int hist[NPAIR];
    __shared__ int basep[NPAIR];
    const int bid = blockIdx.x, tid = threadIdx.x;

    if (bid < PREP_ROUTER_BLOCKS) {
        // ------------------------- router body -------------------------
        float* wsh = smem;   // full-depth skewed W: row k at k*16 + (k>>3)*4

        const int tok0 = bid * RV_TOK;
        const int lane = tid & 63, wv = tid >> 6;
        const int kidx = lane >> 2, ts = lane & 3;
        const int tl = wv * 4 + ts;                // this lane's token
        const int tok = tok0 + tl;

        if (tid < NPAIR) hist[tid] = 0;

        // ---- issue ALL x loads up-front (8 f32x4 -> 32 regs, no LDS) ----
        const float* xrow = x + (size_t)tok * D_ + kidx * 8;
        f32x4 xr[4][2];
        #pragma unroll
        for (int c = 0; c < 4; ++c) {
            xr[c][0] = *(const f32x4*)(xrow + c * 128);
            xr[c][1] = *(const f32x4*)(xrow + c * 128 + 4);
        }

        // ---- stage FULL W once: 1024 (k,half) rows over 4 iterations ----
        #pragma unroll
        for (int it = 0; it < 4; ++it) {
            const int idx = it * RV_THR + tid;     // [0,1024)
            const int k = idx >> 1, h = idx & 1;   // k row, Wr/Wn half
            const float* srcw = (h ? Wn : Wr) + (size_t)k * E_;
            const f32x4 w0 = *(const f32x4*)(srcw);
            const f32x4 w1 = *(const f32x4*)(srcw + 4);
            float* dstw = wsh + k * 16 + (k >> 3) * 4 + h * 8;
            *(f32x4*)(dstw)     = w0;
            *(f32x4*)(dstw + 4) = w1;
        }
        __syncthreads();   // barrier 1: W visible

        float acc[16];  // [0..7]=x.Wr per expert, [8..15]=x.Wn
        #pragma unroll
        for (int c = 0; c < 16; ++c) acc[c] = 0.f;

        #pragma unroll
        for (int c = 0; c < 4; ++c) {
            // fused xb bf16 write straight from regs (16B per lane;
            // 64 lanes cover 4 token rows x 256B contiguous -> coalesced)
            union { __hip_bfloat16 h4[8]; uint4 u; } cv;
            #pragma unroll
            for (int j = 0; j < 4; ++j) {
                cv.h4[j]     = __float2bfloat16(xr[c][0][j]);
                cv.h4[4 + j] = __float2bfloat16(xr[c][1][j]);
            }
            *(uint4*)(xb + (size_t)tok * D_ + c * 128 + kidx * 8) = cv.u;

            // FMAs vs LDS-resident W (chunk base telescopes to c*2112)
            const float* wbase = wsh + c * 2112 + kidx * 132;
            #pragma unroll
            for (int kk = 0; kk < 8; ++kk) {
                const float xav = (kk < 4) ? xr[c][0][kk] : xr[c][1][kk - 4];
                const float* wrow = wbase + kk * 16;
                #pragma unroll
                for (int c4 = 0; c4 < 4; ++c4) {
                    const f32x4 w = *(const f32x4*)(wrow + c4 * 4);
                    #pragma unroll
                    for (int cc = 0; cc < 4; ++cc)
                        acc[c4 * 4 + cc] = fmaf(xav, w[cc], acc[c4 * 4 + cc]);
                }
            }
        }

        // reduce across the 16 kidx lanes (stride 4): xor 4,8,16,32
        #pragma unroll
        for (int off = 4; off < 64; off <<= 1) {
            #pragma unroll
            for (int c = 0; c < 16; ++c)
                acc[c] += __shfl_xor(acc[c], off);
        }

        // ---- top-2 + two-level bucket (LDS hist -> padded global atomics) ----
        int p_ = 0, l_ = 0;
        float gae_ = 0.f, gbe_ = 0.f;
        const bool writer = (lane < 4);
        if (writer) {  // kidx==0 lanes hold full dots for token tl
            float nvv[8];
            #pragma unroll
            for (int e = 0; e < 8; ++e) {
                const float nl = acc[8 + e] + bn[e];
                // jax.nn.softplus = max(z,0) + log1p(exp(-|z|))
                const float sp = fmaxf(nl, 0.f) + log1pf(expf(-fabsf(nl)));
                nvv[e] = acc[e] + br[e] + eps[(size_t)tok * E_ + e] * sp;
            }
            // top-2, lax.top_k tie semantics (lowest index wins ties)
            int i1 = 0; float v1 = nvv[0];
            #pragma unroll
            for (int e = 1; e < 8; ++e)
                if (nvv[e] > v1) { v1 = nvv[e]; i1 = e; }
            int i2 = -1; float v2 = -3.4e38f;
            #pragma unroll
            for (int e = 0; e < 8; ++e)
                if (e != i1 && nvv[e] > v2) { v2 = nvv[e]; i2 = e; }
            const float t  = expf(v2 - v1);
            const float g1 = 1.f / (1.f + t);
            const float g2 = t / (1.f + t);
            const int aa = min(i1, i2), bb = max(i1, i2);
            gae_ = (i1 < i2) ? g1 : g2;   // gate of expert aa
            gbe_ = (i1 < i2) ? g2 : g1;   // gate of expert bb
            p_ = aa * (15 - aa) / 2 + (bb - aa - 1);
            l_ = atomicAdd(&hist[p_], 1);            // LDS atomic (cheap)
        }
        __syncthreads();   // barrier 2: hist complete
        if (tid < NPAIR && hist[tid] > 0)
            basep[tid] = atomicAdd(counts + tid * CPAD, hist[tid]);  // own line
        __syncthreads();   // barrier 3: basep ready
        if (writer)
            entries[(size_t)p_ * CAP + basep[p_] + l_] =
                make_uint4((unsigned)tok, __float_as_uint(gae_),
                           __float_as_uint(gbe_), 0u);
    } else {
        // ------------------- transpose body (64x64 tiles) ------------------
        const int idx = bid - PREP_ROUTER_BLOCKS;   // [0, 512)
        const int e  = idx >> 6;
        const int rem = idx & 63;
        const int d0 = (rem & 7) * 64;
        const int h0 = (rem >> 3) * 64;
        const int tx = tid & 63, ty = tid >> 6;     // 64 x 4
        float (*tile)[65] = reinterpret_cast<float(*)[65]>(smem);  // 16.6 KB

        const float* src = Wk + ((size_t)e * D_ + d0) * D_ + h0;
        #pragma unroll
        for (int r = ty; r < 64; r += 4)
            tile[r][tx] = src[(size_t)r * D_ + tx];
        __syncthreads();
        __hip_bfloat16* dst = wkt + ((size_t)e * D_ + h0) * D_ + d0;
        #pragma unroll
        for (int r = ty; r < 64; r += 4)
            dst[(size_t)r * D_ + tx] = __float2bfloat16(tile[tx][r]);
    }
    // (no fence, no done-counter: kernel boundary publishes everything)
}

// ---------------------------------------------------------------------------
// Kernel 2: pair-grouped expert GEMM, DIRECT output. R11 verbatim (the
// measured best). Split K-step, 2 LDS buffers, depth-2 prefetch via counted
// vmcnt(5), BM=64/BN=128, 3 blocks/CU, inline worklist scan, XCD id decode,
// XOR chunk swizzle, setprio.
// ---------------------------------------------------------------------------
__global__ __launch_bounds__(256, 3) void moe_gemm(
    const __hip_bfloat16* __restrict__ xb,   // [NTOK][D] bf16
    const __hip_bfloat16* __restrict__ wkt,  // [E][D(out)][D(in)] bf16 (B^T)
    const float* __restrict__ bk,            // [E][D]
    const int* __restrict__ counts,          // [NPAIR*CPAD] line-padded
    const uint4* __restrict__ entries,       // [NPAIR][CAP]
    float* __restrict__ out)                 // [NTOK][D] fp32 (fully written)
{
    constexpr int BM = 64, BN = 128, BK = 32;
    constexpr int NT = D_ / BK;  // 16 K-steps
    __shared__ __hip_bfloat16 As[2][BM * BK];       // 2 x 4 KB
    __shared__ __hip_bfloat16 Bs[2][2][BN * BK];    // 2 x 16 KB
    __shared__ uint4 ent[BM];                       // 1 KB   (total 41 KB)

    // id = g*32 + nt*8 + j ; mtile mi = g*8 + j ; XCD = id%8 = j for all 4 nt
    const int id = blockIdx.x;
    const int g = id >> 5, rdec = id & 31;
    const int nt = rdec >> 3;
    const int mi = g * 8 + (rdec & 7);

    const int tid = threadIdx.x;
    const int wave = tid >> 6, lane = tid & 63;

    // ---- inline worklist: lane-parallel scan of ceil(counts/64) ----
    const int cval = (lane < NPAIR) ? counts[lane * CPAD] : 0;
    const int nm = (cval + 63) >> 6;
    int inc = nm;
    #pragma unroll
    for (int d = 1; d < 32; d <<= 1) {
        const int v = __shfl_up(inc, d);
        if (lane >= d) inc += v;
    }
    const int total = __shfl(inc, NPAIR - 1);
    if (mi >= total) return;
    const int ex = inc - nm;   // exclusive prefix for this lane's pair
    const unsigned long long hit =
        __ballot(lane < NPAIR && mi >= ex && mi < ex + nm);
    const int p = __ffsll(hit) - 1;
    const int mt = mi - __shfl(ex, p);
    const int cnt = __shfl(cval, p);

    // decode pair p -> (e1 < e2)
    int e1 = 0, rem = p;
    while (rem >= 7 - e1) { rem -= 7 - e1; ++e1; }
    const int e2 = e1 + 1 + rem;

    if (tid < BM) {
        const int idx = mt * BM + tid;
        ent[tid] = (idx < cnt) ? entries[(size_t)p * CAP + idx]
                               : make_uint4(0u, 0u, 0u, 0u);
    }
    __syncthreads();

    const int quad = lane >> 4, lr = lane & 15;
    const int wm = wave >> 1, wn = wave & 1;   // wave tile: rows wm*32, cols wn*64

    // --- staging geometry (64B contiguous per row, 16 rows per call) ---
    const int r16 = lane >> 2;
    const int csel = (lane & 3) ^ ((lane >> 3) & 3);   // swizzled 16B chunk
    const size_t tA0 = ent[wave * 16 + r16].x;
    const __hip_bfloat16* gA0 = xb + tA0 * D_ + csel * 8;
    const __hip_bfloat16* gB1 = wkt + ((size_t)e1 * D_ + nt * BN + wave * 32 + r16) * D_ + csel * 8;
    const __hip_bfloat16* gB2 = wkt + ((size_t)e2 * D_ + nt * BN + wave * 32 + r16) * D_ + csel * 8;

    // read-side swizzled slot (per-lane constant): quad ^ ((lr>>1)&3)
    const int so = (quad ^ ((lr >> 1) & 3)) * 8;

    f32x4 accA[2][4], accB[2][4];
    #pragma unroll
    for (int i = 0; i < 2; ++i)
        #pragma unroll
        for (int j = 0; j < 4; ++j) {
            accA[i][j] = (f32x4){0.f, 0.f, 0.f, 0.f};
            accB[i][j] = (f32x4){0.f, 0.f, 0.f, 0.f};
        }

    // 5 async loads per wave per STAGE -> vmcnt counts in units of 5
#define STAGE(buf, k0) do {                                        \
        __hip_bfloat16* aB  = &As[buf][wave * 512];                \
        __hip_bfloat16* b1B = &Bs[buf][0][wave * 1024];            \
        __hip_bfloat16* b2B = &Bs[buf][1][wave * 1024];            \
        async_load16(gA0 + (k0), aB);                              \
        async_load16(gB1 + (k0), b1B);                             \
        async_load16(gB1 + 16 * D_ + (k0), b1B + 512);             \
        async_load16(gB2 + (k0), b2B);                             \
        async_load16(gB2 + 16 * D_ + (k0), b2B + 512);             \
    } while (0)

#define READS(buf) do {                                                        \
        _Pragma("unroll")                                                      \
        for (int i = 0; i < 2; ++i)                                            \
            a[i] = *(const short8*)(&As[buf][(wm * 32 + i * 16 + lr) * 32 + so]); \
        _Pragma("unroll")                                                      \
        for (int j = 0; j < 4; ++j) {                                          \
            b1v[j] = *(const short8*)(&Bs[buf][0][(wn * 64 + j * 16 + lr) * 32 + so]); \
            b2v[j] = *(const short8*)(&Bs[buf][1][(wn * 64 + j * 16 + lr) * 32 + so]); \
        }                                                                      \
    } while (0)

#define MFMAS() do {                                                           \
        __builtin_amdgcn_s_setprio(1);                                         \
        _Pragma("unroll")                                                      \
        for (int i = 0; i < 2; ++i)                                            \
            _Pragma("unroll")                                                  \
            for (int j = 0; j < 4; ++j) {                                      \
                accA[i][j] = __builtin_amdgcn_mfma_f32_16x16x32_bf16(          \
                    a[i], b1v[j], accA[i][j], 0, 0, 0);                        \
                accB[i][j] = __builtin_amdgcn_mfma_f32_16x16x32_bf16(          \
                    a[i], b2v[j], accB[i][j], 0, 0, 0);                        \
            }                                                                  \
        __builtin_amdgcn_s_setprio(0);                                         \
    } while (0)

    // prologue: tiles 0 and 1 in flight (10 outstanding VMEM ops per wave)
    STAGE(0, 0);
    STAGE(1, BK);

    // steady state (split K-step): tile t lands -> read to regs -> drain
    // lgkm -> barrier -> refill the SAME buffer with tile t+2 -> MFMA.
    for (int t = 0; t < NT - 1; ++t) {
        short8 a[2], b1v[4], b2v[4];
        asm volatile("s_waitcnt vmcnt(5)" ::: "memory");
        __builtin_amdgcn_s_barrier();
        READS(t & 1);
        asm volatile("s_waitcnt lgkmcnt(0)" ::: "memory");
        __builtin_amdgcn_s_barrier();
        if (t + 2 < NT) STAGE(t & 1, (t + 2) * BK);
        MFMAS();
    }
    {
        short8 a[2], b1v[4], b2v[4];
        asm volatile("s_waitcnt vmcnt(0)" ::: "memory");
        __builtin_amdgcn_s_barrier();
        READS((NT - 1) & 1);
        MFMAS();
    }

#undef STAGE
#undef READS
#undef MFMAS

    const int colbase = nt * BN + wn * 64 + lr;
    float bkA[4], bkB[4];
    #pragma unroll
    for (int j = 0; j < 4; ++j) {
        bkA[j] = bk[e1 * D_ + colbase + j * 16];
        bkB[j] = bk[e2 * D_ + colbase + j * 16];
    }

    #pragma unroll
    for (int i = 0; i < 2; ++i) {
        #pragma unroll
        for (int rr = 0; rr < 4; ++rr) {
            const int row = wm * 32 + i * 16 + quad * 4 + rr;  // C: row = quad*4+reg
            if (mt * BM + row < cnt) {
                const uint4 en = ent[row];
                const float ga = __uint_as_float(en.y);
                const float gb = __uint_as_float(en.z);
                float* orow = out + (size_t)en.x * D_ + colbase;
                #pragma unroll
                for (int j = 0; j < 4; ++j)
                    orow[j * 16] = ga * (accA[i][j][rr] + bkA[j])
                                 + gb * (accB[i][j][rr] + bkB[j]);
            }
        }
    }
}

// ---------------------------------------------------------------------------
// Launch: 3 dispatches: memset, fused prep, gemm (worklist inlined).
// ---------------------------------------------------------------------------
extern "C" void kernel_launch(void* const* d_in, const int* in_sizes, int n_in,
                              void* d_out, int out_size, void* d_ws, size_t ws_size,
                              hipStream_t stream) {
    const float* x   = (const float*)d_in[0];
    const float* eps = (const float*)d_in[1];
    const float* Wr  = (const float*)d_in[2];
    const float* br  = (const float*)d_in[3];
    const float* Wn  = (const float*)d_in[4];
    const float* bn  = (const float*)d_in[5];
    const float* Wk  = (const float*)d_in[6];
    const float* bk  = (const float*)d_in[7];
    float* out = (float*)d_out;

    // workspace layout (256B-aligned): ~28 MB total
    char* ws = (char*)d_ws;
    size_t off = 0;
    int* counts = (int*)(ws + off);                     off += 8192;  // NPAIR*CPAD ints (3.5KB), padded
    uint4* entries = (uint4*)(ws + off);                off += (size_t)NPAIR * CAP * 16;  // 7.3 MiB
    __hip_bfloat16* xb = (__hip_bfloat16*)(ws + off);   off += (size_t)NTOK * D_ * 2;     // 16 MiB
    __hip_bfloat16* wkt = (__hip_bfloat16*)(ws + off);  off += (size_t)E_ * D_ * D_ * 2;  // 4 MiB
    (void)ws_size;

    hipMemsetAsync(counts, 0, 8192, stream);   // zeroes counts[]

    prep_kernel<<<dim3(PREP_BLOCKS), dim3(256), 0, stream>>>(
        x, eps, Wr, br, Wn, bn, Wk, xb, wkt, counts, entries);
    moe_gemm<<<dim3(GEMM_MTILES * 4), dim3(256), 0, stream>>>(
        xb, wkt, bk, counts, entries, out);
}